// Round 15
// baseline (243.868 us; speedup 1.0000x reference)
//
#include <hip/hip_runtime.h>
#include <hip/hip_bf16.h>

// NT-Xent (CLIP) loss, N=16384 D=256 fp32 in, 3 fp32 out.
// loss_vu = mean_i( log(sum_j exp(sim_ij)) - sim_ii ), sim = (v̂·û^T)/T
// Logits bounded by 1/T=14.29 -> no max subtraction needed.
//
// R10-R14: FRAGMENT-MAJOR layout, LDS-free barrier-free K2:
//     345 -> 196 -> 155 -> 153us (16x16x32, depth-2 B ring, A resident).
// R15: T15 epilogue slicing -- spill, reverted. R16: 32x32x16 -- 165us
//     (4 acc chains x 16 deep can't cover MFMA latency at 2 waves/SIMD;
//     16x16's 16 chains x 8 deep is the better ILP shape). Reverted.
// R17: K1 WRITE COALESCING. Totals show ~70-84us outside K2 for all
//     fragment-major rounds vs ~50us with row-major K1: the scattered
//     per-lane 16B fragment writes cost ~25-30us. New K1: block = 64
//     rows; phase 1 = R14's verified wave-per-2-rows norm reduce (x8),
//     norms+diag via LDS; phase 2 = thread t writes chunk lp=t of each
//     1KB fragment -> frag_base + t*16 = fully coalesced 32KB streams.
//     Sources re-read from L2 (128KB block working set, L2-hot).
//     K2 = R14 verbatim. Gates: absmax 0, K2 150-158us, total <= 210us.

#define D_DIM 256

constexpr float INV_T = 1.0f / 0.07f;
constexpr float EXP2_SCALE = 1.44269504088896340736f / 0.07f;  // log2(e)/T

typedef __bf16 bf16x8 __attribute__((ext_vector_type(8)));
typedef float f32x4 __attribute__((ext_vector_type(4)));

// ---------------------------------------------------------------------------
// Kernel 1: L2-normalize fp32 -> bf16 in 16x16x32 FRAGMENT-MAJOR layout,
// with coalesced fragment writes.
// Block = 64 rows (4 groups of 16). Fragment (g,ks) = 1KB: position
// lp = quad*16+l15 holds row g*16+l15, k = ks*32+quad*8..+8 (R10..R14-
// verified format; only the writer changed).
// Phase 1 (x8): wave = 2 rows (sub=lane>>5, pos=lane&31), 32-lane
//   butterfly for |v|^2, |u|^2, v.u; norms -> LDS, diag -> global.
// Phase 2 (x8): thread t writes chunk c = i*256+t: gl=c>>9, ks=(c&511)>>6,
//   lp=c&63 -> dst = ((blk*4+gl)*8+ks)*512 + lp*8: consecutive t ->
//   consecutive 16B -> fully coalesced. Source rows L2-hot from phase 1.
// V' pre-scaled by EXP2_SCALE; zeroes row/colsum + partials.
// ---------------------------------------------------------------------------
__global__ __launch_bounds__(256) void normalize_kernel(
    const float* __restrict__ img, const float* __restrict__ txt,
    __hip_bfloat16* __restrict__ Vf, __hip_bfloat16* __restrict__ Uf,
    float* __restrict__ diagarr, float* __restrict__ rowsum,
    float* __restrict__ colsum, float* __restrict__ partials) {
  __shared__ float snv[64], snu[64];

  const int t = threadIdx.x;
  const int wave = t >> 6;
  const int lane = t & 63;
  const int sub = lane >> 5;   // 0/1: which of the wave's two rows
  const int pos = lane & 31;   // 8-elem chunk index within the row
  const int rowblk = blockIdx.x * 64;

  // ---- phase 1: norms + diag for 64 rows (8 iterations x 8 rows) ----
#pragma unroll
  for (int it = 0; it < 8; ++it) {
    const int rloc = it * 8 + wave * 2 + sub;
    const size_t base = (size_t)(rowblk + rloc) * D_DIM + pos * 8;

    const float4 i0 = *reinterpret_cast<const float4*>(&img[base]);
    const float4 i1 = *reinterpret_cast<const float4*>(&img[base + 4]);
    const float4 t0 = *reinterpret_cast<const float4*>(&txt[base]);
    const float4 t1 = *reinterpret_cast<const float4*>(&txt[base + 4]);

    float a = i0.x * i0.x + i0.y * i0.y + i0.z * i0.z + i0.w * i0.w +
              i1.x * i1.x + i1.y * i1.y + i1.z * i1.z + i1.w * i1.w;
    float b = t0.x * t0.x + t0.y * t0.y + t0.z * t0.z + t0.w * t0.w +
              t1.x * t1.x + t1.y * t1.y + t1.z * t1.z + t1.w * t1.w;
    float d = i0.x * t0.x + i0.y * t0.y + i0.z * t0.z + i0.w * t0.w +
              i1.x * t1.x + i1.y * t1.y + i1.z * t1.z + i1.w * t1.w;
#pragma unroll
    for (int off = 1; off < 32; off <<= 1) {
      a += __shfl_xor(a, off, 64);
      b += __shfl_xor(b, off, 64);
      d += __shfl_xor(d, off, 64);
    }
    if (pos == 0) {
      const float si = 1.0f / fmaxf(sqrtf(a), 1e-8f);
      const float st = 1.0f / fmaxf(sqrtf(b), 1e-8f);
      snv[rloc] = si * EXP2_SCALE;  // V pre-scaled by log2e/T
      snu[rloc] = st;
      diagarr[rowblk + rloc] = d * si * st;  // unscaled v̂·û
    }
  }

  if (t < 64) {
    rowsum[rowblk + t] = 0.0f;
    colsum[rowblk + t] = 0.0f;
  }
  if (blockIdx.x == 0 && t < 4) partials[t] = 0.0f;
  __syncthreads();

  // ---- phase 2: coalesced fragment writes (8 chunks per array) ----
#pragma unroll
  for (int i = 0; i < 8; ++i) {
    const int c = i * 256 + t;       // chunk id in [0, 2048)
    const int gl = c >> 9;           // local group 0..3
    const int cc = c & 511;
    const int ks = cc >> 6;          // fragment k-slice 0..7
    const int lp = cc & 63;          // position within fragment
    const int l15 = lp & 15;
    const int qd = lp >> 4;
    const size_t sbase =
        (size_t)(rowblk + gl * 16 + l15) * D_DIM + ks * 32 + qd * 8;
    const size_t dst =
        ((size_t)(blockIdx.x * 4 + gl) * 8 + ks) * 512 + lp * 8;

    const float4 x0 = *reinterpret_cast<const float4*>(&img[sbase]);
    const float4 x1 = *reinterpret_cast<const float4*>(&img[sbase + 4]);
    const float vs = snv[gl * 16 + l15];
    __hip_bfloat16 vb8[8] = {
        __float2bfloat16(x0.x * vs), __float2bfloat16(x0.y * vs),
        __float2bfloat16(x0.z * vs), __float2bfloat16(x0.w * vs),
        __float2bfloat16(x1.x * vs), __float2bfloat16(x1.y * vs),
        __float2bfloat16(x1.z * vs), __float2bfloat16(x1.w * vs)};
    *reinterpret_cast<uint4*>(&Vf[dst]) = *reinterpret_cast<uint4*>(vb8);

    const float4 y0 = *reinterpret_cast<const float4*>(&txt[sbase]);
    const float4 y1 = *reinterpret_cast<const float4*>(&txt[sbase + 4]);
    const float us = snu[gl * 16 + l15];
    __hip_bfloat16 ub8[8] = {
        __float2bfloat16(y0.x * us), __float2bfloat16(y0.y * us),
        __float2bfloat16(y0.z * us), __float2bfloat16(y0.w * us),
        __float2bfloat16(y1.x * us), __float2bfloat16(y1.y * us),
        __float2bfloat16(y1.z * us), __float2bfloat16(y1.w * us)};
    *reinterpret_cast<uint4*>(&Uf[dst]) = *reinterpret_cast<uint4*>(ub8);
  }
}

// ---------------------------------------------------------------------------
// Kernel 2 (R14 verbatim, best: 153us): barrier-free streaming MFMA GEMM +
// online exp2 sums. Block b: row-strip rb = b>>1 (64 rows, groups
// 4rb..4rb+3), col-half ch = b&1 (8192 cols = 16 jt of 512). 8 waves;
// wave w covers cols [jt*512 + w*64, +64). A-frags a[4][8] (128 VGPR)
// resident. B: depth-2 ring bb[2][4]; at ks issue load(ks+1) into the
// other bank, sched_barrier(0) pin, consume bank ks&1; ks=7 prefetches
// next jt's ks0 (covered by the per-jt epilogue). colsum: LDS colbuf[8192]
// single-writer stores, one coalesced atomic flush post-loop.
// acc layout (verified): row = mi*16 + quad*4 + r, col = ni*16 + l15.
// ---------------------------------------------------------------------------
__global__ __launch_bounds__(512, 2) void gemm_lse_kernel(
    const __hip_bfloat16* __restrict__ Vf, const __hip_bfloat16* __restrict__ Uf,
    float* __restrict__ rowsum, float* __restrict__ colsum, int n) {
  __shared__ float colbuf[8192];  // 32 KB; each entry written exactly once

  const int tid = threadIdx.x;
  const int lane = tid & 63;
  const int w = tid >> 6;        // 0..7
  const int quad = lane >> 4;
  const int l15 = lane & 15;
  const int rb = blockIdx.x >> 1;   // row strip
  const int ch = blockIdx.x & 1;    // col half (constant per XCD)
  const int njt = n >> 10;          // j-tiles per block (16)

  // A fragments for rows [rb*64, +64): groups 4rb..4rb+3, all K, once.
  bf16x8 a[4][8];
#pragma unroll
  for (int mi = 0; mi < 4; ++mi)
#pragma unroll
    for (int ks = 0; ks < 8; ++ks)
      a[mi][ks] = *reinterpret_cast<const bf16x8*>(
          Vf + (size_t)((4 * rb + mi) * 8 + ks) * 512 + lane * 8);

  float rs[4][4] = {};  // rowsum partials (mi, r), all jt

  // B base for this wave: col group = jt*32 + w*4 + ni; frag at
  // (group*8 + ks)*512 + lane*8.
  const __hip_bfloat16* Ub = Uf + (size_t)(w * 4) * 8 * 512 + lane * 8;
  const size_t jstart = (size_t)(ch * njt) * (32 * 8 * 512);

  // Depth-2 ring. Prologue: jt0 ks0 -> bank 0.
  bf16x8 bb[2][4];
#pragma unroll
  for (int ni = 0; ni < 4; ++ni)
    bb[0][ni] =
        *reinterpret_cast<const bf16x8*>(Ub + jstart + (size_t)(ni * 8) * 512);

  for (int jl = 0; jl < njt; ++jl) {
    const size_t jb = jstart + (size_t)jl * (32 * 8 * 512);
    const size_t jbn = (jl < njt - 1) ? jb + 32 * 8 * 512 : jstart;  // wrap
    f32x4 acc[4][4] = {};

#pragma unroll
    for (int ks = 0; ks < 8; ++ks) {
      // issue load for step ks+1 into the other bank (free since ks-1)
      {
        const size_t pjb = (ks < 7) ? jb : jbn;
        const int pks = (ks < 7) ? ks + 1 : 0;
#pragma unroll
        for (int ni = 0; ni < 4; ++ni)
          bb[(ks + 1) & 1][ni] = *reinterpret_cast<const bf16x8*>(
              Ub + pjb + (size_t)(ni * 8 + pks) * 512);
        __builtin_amdgcn_sched_barrier(0);
      }
      // consume bank ks&1 (waitcnt for its step-(ks-1) loads)
#pragma unroll
      for (int mi = 0; mi < 4; ++mi)
#pragma unroll
        for (int ni = 0; ni < 4; ++ni)
          acc[mi][ni] = __builtin_amdgcn_mfma_f32_16x16x32_bf16(
              a[mi][ks], bb[ks & 1][ni], acc[mi][ni], 0, 0, 0);
    }

    // per-jt epilogue: exp2, rowsum regs, colsum -> LDS (no VMEM here) --
    // also the latency cover for the next jt's ks0 prefetch.
    float cs0 = 0.f, cs1 = 0.f, cs2 = 0.f, cs3 = 0.f;
#pragma unroll
    for (int mi = 0; mi < 4; ++mi)
#pragma unroll
      for (int r = 0; r < 4; ++r) {
        const float e0 = __builtin_amdgcn_exp2f(acc[mi][0][r]);
        const float e1 = __builtin_amdgcn_exp2f(acc[mi][1][r]);
        const float e2 = __builtin_amdgcn_exp2f(acc[mi][2][r]);
        const float e3 = __builtin_amdgcn_exp2f(acc[mi][3][r]);
        rs[mi][r] += e0 + e1 + e2 + e3;
        cs0 += e0; cs1 += e1; cs2 += e2; cs3 += e3;
      }
    float csa[4] = {cs0, cs1, cs2, cs3};
#pragma unroll
    for (int ni = 0; ni < 4; ++ni) {
      float c = csa[ni];
      c += __shfl_xor(c, 16, 64);
      c += __shfl_xor(c, 32, 64);
      if (lane < 16)
        colbuf[jl * 512 + w * 64 + ni * 16 + l15] = c;  // single writer
    }
  }

  // flush colsum once: coalesced atomics, off the jt critical path.
  __syncthreads();
  const int colbase = ch * (n >> 1);
  for (int i = tid; i < (n >> 1); i += 512)
    atomicAdd(&colsum[colbase + i], colbuf[i]);

  // final rowsum: reduce over the 16 l15 lanes; waves+col-halves meet
  // via atomics.
#pragma unroll
  for (int mi = 0; mi < 4; ++mi)
#pragma unroll
    for (int r = 0; r < 4; ++r) {
      float v = rs[mi][r];
      v += __shfl_xor(v, 1, 64);
      v += __shfl_xor(v, 2, 64);
      v += __shfl_xor(v, 4, 64);
      v += __shfl_xor(v, 8, 64);
      if (l15 == 0)
        atomicAdd(&rowsum[rb * 64 + mi * 16 + quad * 4 + r], v);
    }
}

// ---------------------------------------------------------------------------
// Kernel 3a: parallel partial reduction of log(rowsum), log(colsum), diag.
// ---------------------------------------------------------------------------
__global__ __launch_bounds__(256) void finalize_partial(
    const float* __restrict__ rowsum, const float* __restrict__ colsum,
    const float* __restrict__ diagarr, float* __restrict__ partials, int n) {
  float sr = 0.0f, sc = 0.0f, sd = 0.0f;
  for (int i = blockIdx.x * 256 + threadIdx.x; i < n; i += gridDim.x * 256) {
    sr += __logf(rowsum[i]);
    sc += __logf(colsum[i]);
    sd += diagarr[i];
  }
#pragma unroll
  for (int off = 1; off < 64; off <<= 1) {
    sr += __shfl_xor(sr, off, 64);
    sc += __shfl_xor(sc, off, 64);
    sd += __shfl_xor(sd, off, 64);
  }
  if ((threadIdx.x & 63) == 0) {
    atomicAdd(&partials[0], sr);
    atomicAdd(&partials[1], sc);
    atomicAdd(&partials[2], sd);
  }
}

// ---------------------------------------------------------------------------
// Kernel 3b: final 3-float output from the totals.
// ---------------------------------------------------------------------------
__global__ void finalize_final(const float* __restrict__ partials,
                               float* __restrict__ out, int n) {
  const float invN = 1.0f / (float)n;
  const float dm = partials[2] * INV_T * invN;  // mean diag logit
  const float lvu = partials[0] * invN - dm;
  const float luv = partials[1] * invN - dm;
  out[0] = 0.5f * lvu + 0.5f * luv;  // WEIGHT = 0.5
  out[1] = lvu;
  out[2] = luv;
}

extern "C" void kernel_launch(void* const* d_in, const int* in_sizes, int n_in,
                              void* d_out, int out_size, void* d_ws, size_t ws_size,
                              hipStream_t stream) {
  const float* img = (const float*)d_in[0];
  const float* txt = (const float*)d_in[1];
  float* out = (float*)d_out;
  const int N = in_sizes[0] / D_DIM;  // 16384

  char* ws = (char*)d_ws;
  __hip_bfloat16* Vf = (__hip_bfloat16*)ws;                             // 8MB
  __hip_bfloat16* Uf = (__hip_bfloat16*)(ws + (size_t)N * D_DIM * 2);   // 8MB
  float* rowsum = (float*)(ws + (size_t)N * D_DIM * 4);
  float* colsum = rowsum + N;
  float* diagarr = colsum + N;
  float* partials = diagarr + N;  // 4 floats

  // rowsum/colsum/partials zeroed inside normalize_kernel
  normalize_kernel<<<N / 64, 256, 0, stream>>>(img, txt, Vf, Uf, diagarr,
                                               rowsum, colsum, partials);

  gemm_lse_kernel<<<N / 32, 512, 0, stream>>>(Vf, Uf, rowsum, colsum, N);

  finalize_partial<<<64, 256, 0, stream>>>(rowsum, colsum, diagarr, partials,
                                           N);
  finalize_final<<<1, 1, 0, stream>>>(partials, out, N);
}